// Round 5
// baseline (466.580 us; speedup 1.0000x reference)
//
#include <hip/hip_runtime.h>
#include <hip/hip_bf16.h>
#include <cstdint>
#include <cstddef>

#define BN_EPS 1e-3f

typedef __attribute__((ext_vector_type(8))) short bf16x8;
typedef __attribute__((ext_vector_type(4))) float f32x4;

__device__ __forceinline__ float blo(unsigned u) {
  union { unsigned i; float f; } v; v.i = u << 16; return v.f;
}
__device__ __forceinline__ float bhi(unsigned u) {
  union { unsigned i; float f; } v; v.i = u & 0xffff0000u; return v.f;
}
__device__ __forceinline__ unsigned pk2(float a, float b) {
  __hip_bfloat162 t = __float22bfloat162_rn(make_float2(a, b));
  return *reinterpret_cast<unsigned*>(&t);
}
__device__ __forceinline__ void acc_pk(float* acc, uint4 u) {
  acc[0] += blo(u.x); acc[1] += bhi(u.x);
  acc[2] += blo(u.y); acc[3] += bhi(u.y);
  acc[4] += blo(u.z); acc[5] += bhi(u.z);
  acc[6] += blo(u.w); acc[7] += bhi(u.w);
}

// ---------------------------------------------------------------------------
// Embedding MFMA GEMM (A [N][96] bf16 global, Bt [128][96] bf16).
// h = relu(acc + bias); hb = bf16(h). 64x128 per block, 4 waves 2x2.
// ---------------------------------------------------------------------------
template<int K>
__global__ __launch_bounds__(256) void gemm_emb_mfma(
    const __hip_bfloat16* __restrict__ A,
    const __hip_bfloat16* __restrict__ Bt,
    const float* __restrict__ bias,
    float* __restrict__ h,
    __hip_bfloat16* __restrict__ hb, int N)
{
  const int tid  = threadIdx.x;
  const int w    = tid >> 6, lane = tid & 63;
  const int wr   = w >> 1,   wc   = w & 1;
  const int m0   = blockIdx.x * 64;
  const int lr   = lane & 15;
  const int kg   = lane >> 4;

  f32x4 acc[2][4] = {};
  const int rowA0 = m0 + wr * 32 + lr;

  #pragma unroll
  for (int ks = 0; ks < K / 32; ks++) {
    const int k0 = ks * 32 + kg * 8;
    bf16x8 a[2], b[4];
    #pragma unroll
    for (int m = 0; m < 2; m++) {
      int r = rowA0 + m * 16;
      r = (r < N) ? r : 0;
      a[m] = *reinterpret_cast<const bf16x8*>(&A[(size_t)r * K + k0]);
    }
    #pragma unroll
    for (int n = 0; n < 4; n++) {
      int c = wc * 64 + n * 16 + lr;
      b[n] = *reinterpret_cast<const bf16x8*>(&Bt[(size_t)c * K + k0]);
    }
    #pragma unroll
    for (int m = 0; m < 2; m++)
      #pragma unroll
      for (int n = 0; n < 4; n++)
        acc[m][n] = __builtin_amdgcn_mfma_f32_16x16x32_bf16(a[m], b[n], acc[m][n], 0, 0, 0);
  }

  #pragma unroll
  for (int n = 0; n < 4; n++) {
    const int c = wc * 64 + n * 16 + lr;
    const float bb = bias[c];
    #pragma unroll
    for (int m = 0; m < 2; m++) {
      #pragma unroll
      for (int j = 0; j < 4; j++) {
        int grow = m0 + wr * 32 + m * 16 + kg * 4 + j;
        if (grow < N) {
          float v = fmaxf(acc[m][n][j] + bb, 0.f);
          h[(size_t)grow * 128 + c]  = v;
          hb[(size_t)grow * 128 + c] = __float2bfloat16(v);
        }
      }
    }
  }
}

// ---------------------------------------------------------------------------
// Fused conv layer: gather S-tile (segment_sum of hbi[col]) + T-tile into LDS,
// then 64x128 MFMA with fused epilogue:
//   h += relu(acc/deg * bn_scale + (bc*bn_scale + beta)); hbo = bf16(h)
// hbi/hbo are DISTINCT buffers (ping-pong) — avoids cross-block RAW race.
// LDS A-tile [64][200] bf16 (pad 192->200: 2-way bank alias only).
// ---------------------------------------------------------------------------
__global__ __launch_bounds__(256) void conv_fused(
    const __hip_bfloat16* __restrict__ hbi,
    const int* __restrict__ row_ptr,
    const int* __restrict__ csr_col,
    const __hip_bfloat16* __restrict__ Tb,    // [N][64]
    const __hip_bfloat16* __restrict__ Wct,   // [128][192]
    const float* __restrict__ deg,
    const float* __restrict__ bc,
    const float* __restrict__ gamma,
    const float* __restrict__ beta,
    float* __restrict__ h,
    __hip_bfloat16* __restrict__ hbo, int N)
{
  constexpr int K   = 192;
  constexpr int LDK = 200;
  __shared__ __hip_bfloat16 As[64 * LDK];   // 25.6 KB

  const int tid = threadIdx.x;
  const int m0  = blockIdx.x * 64;

  // ---- gather phase: 16 groups x 16 lanes; group g rows {g, g+16, g+32, g+48}
  {
    const int g   = tid >> 4;
    const int gl  = tid & 15;
    const int wl  = tid & 63;
    const int gb  = wl & ~15;       // group base lane within wave (for shfl)
    for (int rr = 0; rr < 4; rr++) {
      const int r  = g + rr * 16;
      const int gr = m0 + r;
      float acc[8] = {};
      if (gr < N) {
        const int s   = row_ptr[gr];
        const int len = row_ptr[gr + 1] - s;
        for (int b = 0; b < len; b += 16) {
          const int m  = min(16, len - b);
          const int cv = (gl < m) ? csr_col[s + b + gl] : 0;
          int j = 0;
          for (; j + 8 <= m; j += 8) {
            uint4 u[8];
            #pragma unroll
            for (int t = 0; t < 8; t++) {
              int c = __shfl(cv, gb + j + t);
              u[t] = *reinterpret_cast<const uint4*>(&hbi[(size_t)c * 128 + gl * 8]);
            }
            #pragma unroll
            for (int t = 0; t < 8; t++) acc_pk(acc, u[t]);
          }
          for (; j + 4 <= m; j += 4) {
            uint4 u[4];
            #pragma unroll
            for (int t = 0; t < 4; t++) {
              int c = __shfl(cv, gb + j + t);
              u[t] = *reinterpret_cast<const uint4*>(&hbi[(size_t)c * 128 + gl * 8]);
            }
            #pragma unroll
            for (int t = 0; t < 4; t++) acc_pk(acc, u[t]);
          }
          for (; j < m; ++j) {
            int c = __shfl(cv, gb + j);
            uint4 u = *reinterpret_cast<const uint4*>(&hbi[(size_t)c * 128 + gl * 8]);
            acc_pk(acc, u);
          }
        }
      }
      uint4 o;
      o.x = pk2(acc[0], acc[1]); o.y = pk2(acc[2], acc[3]);
      o.z = pk2(acc[4], acc[5]); o.w = pk2(acc[6], acc[7]);
      *reinterpret_cast<uint4*>(&As[r * LDK + gl * 8]) = o;
    }
  }
  // ---- T-tile copy: 64 rows x 64 cols bf16 = 512 x 16B chunks
  #pragma unroll
  for (int it = 0; it < 2; it++) {
    int idx = tid + it * 256;
    int r   = idx >> 3;
    int ko  = (idx & 7) * 8;
    int gr  = m0 + r;
    uint4 v = make_uint4(0, 0, 0, 0);
    if (gr < N) v = *reinterpret_cast<const uint4*>(&Tb[(size_t)gr * 64 + ko]);
    *reinterpret_cast<uint4*>(&As[r * LDK + 128 + ko]) = v;
  }
  __syncthreads();

  // ---- MFMA phase
  const int w    = tid >> 6, lane = tid & 63;
  const int wr   = w >> 1,   wc   = w & 1;
  const int lr   = lane & 15;
  const int kg   = lane >> 4;

  f32x4 acc[2][4] = {};
  #pragma unroll
  for (int ks = 0; ks < K / 32; ks++) {
    const int k0 = ks * 32 + kg * 8;
    bf16x8 a[2], b[4];
    #pragma unroll
    for (int m = 0; m < 2; m++) {
      int r = wr * 32 + lr + m * 16;
      a[m] = *reinterpret_cast<const bf16x8*>(&As[r * LDK + k0]);
    }
    #pragma unroll
    for (int n = 0; n < 4; n++) {
      int c = wc * 64 + n * 16 + lr;
      b[n] = *reinterpret_cast<const bf16x8*>(&Wct[(size_t)c * K + k0]);
    }
    #pragma unroll
    for (int m = 0; m < 2; m++)
      #pragma unroll
      for (int n = 0; n < 4; n++)
        acc[m][n] = __builtin_amdgcn_mfma_f32_16x16x32_bf16(a[m], b[n], acc[m][n], 0, 0, 0);
  }

  const float rs = rsqrtf(1.f + BN_EPS);
  #pragma unroll
  for (int n = 0; n < 4; n++) {
    const int c   = wc * 64 + n * 16 + lr;
    const float sc  = gamma[c] * rs;
    const float ofs = bc[c] * sc + beta[c];
    #pragma unroll
    for (int m = 0; m < 2; m++) {
      #pragma unroll
      for (int j = 0; j < 4; j++) {
        int grow = m0 + wr * 32 + m * 16 + kg * 4 + j;
        if (grow < N) {
          float id = 1.f / deg[grow];
          float v  = acc[m][n][j] * sc * id + ofs;
          float hn = h[(size_t)grow * 128 + c] + fmaxf(v, 0.f);
          h[(size_t)grow * 128 + c]   = hn;
          hbo[(size_t)grow * 128 + c] = __float2bfloat16(hn);
        }
      }
    }
  }
}

// ---------------------------------------------------------------------------
// One-shot prep: xb [N][96] bf16 (pad 92->96), Wet [128][96] bf16 (transposed,
// padded), Wct [L][128][192] bf16 (transposed), zero cnt/fill_cnt.
// ---------------------------------------------------------------------------
__global__ void prep_all(const float* __restrict__ x, __hip_bfloat16* __restrict__ xb,
                         const float* __restrict__ W_emb, __hip_bfloat16* __restrict__ Wet,
                         const float* __restrict__ Wc, __hip_bfloat16* __restrict__ Wct,
                         int* __restrict__ cnt,
                         int N, int Fn, int Kp, int H, int L, int Kc, int total)
{
  int i = blockIdx.x * 256 + threadIdx.x;
  if (i < N * Kp) {
    int r = i / Kp, k = i - r * Kp;
    xb[i] = __float2bfloat16(k < Fn ? x[(size_t)r * Fn + k] : 0.f);
  } else if (i < N * Kp + H * Kp) {
    int j = i - N * Kp;
    int c = j / Kp, k = j - c * Kp;
    Wet[j] = __float2bfloat16(k < Fn ? W_emb[(size_t)k * H + c] : 0.f);
  } else if (i < total) {
    int j = i - N * Kp - H * Kp;
    int l   = j / (H * Kc);
    int rem = j - l * (H * Kc);
    int c   = rem / Kc;
    int k   = rem - c * Kc;
    Wct[j] = __float2bfloat16(Wc[(size_t)l * Kc * H + (size_t)k * H + c]);
  }
  if (i < 2 * N) cnt[i] = 0;
}

// ---------------------------------------------------------------------------
// CSR build
// ---------------------------------------------------------------------------
__global__ void hist_kernel(const int* __restrict__ rows, int* __restrict__ cnt, int E) {
  int e = blockIdx.x * 256 + threadIdx.x;
  if (e < E) atomicAdd(&cnt[rows[e]], 1);
}

__global__ __launch_bounds__(1024) void scan_kernel(const int* __restrict__ cnt,
                                                    int* __restrict__ row_ptr, int N) {
  __shared__ int wsum[16];
  __shared__ int woff[16];
  __shared__ int carry;
  const int tid  = threadIdx.x;
  const int lane = tid & 63, wid = tid >> 6;
  if (tid == 0) { carry = 0; row_ptr[0] = 0; }
  __syncthreads();
  for (int base = 0; base < N; base += 8192) {
    int c = carry;
    int v[8]; int s = 0;
    #pragma unroll
    for (int i = 0; i < 8; i++) {
      int idx = base + tid * 8 + i;
      v[i] = (idx < N) ? cnt[idx] : 0;
      s += v[i];
    }
    int sc = s;
    #pragma unroll
    for (int o = 1; o < 64; o <<= 1) {
      int u = __shfl_up(sc, o);
      if (lane >= o) sc += u;
    }
    if (lane == 63) wsum[wid] = sc;
    __syncthreads();
    if (tid == 0) {
      int run = 0;
      for (int i = 0; i < 16; i++) { int t = wsum[i]; woff[i] = run; run += t; }
      carry = c + run;
    }
    __syncthreads();
    int run = c + woff[wid] + (sc - s);
    #pragma unroll
    for (int i = 0; i < 8; i++) {
      int idx = base + tid * 8 + i;
      run += v[i];
      if (idx < N) row_ptr[idx + 1] = run;
    }
  }
}

__global__ void fill_kernel(const int* __restrict__ rows, const int* __restrict__ cols,
                            const int* __restrict__ row_ptr, int* __restrict__ fill_cnt,
                            int* __restrict__ csr_col, int* __restrict__ csr_eid, int E) {
  int e = blockIdx.x * 256 + threadIdx.x;
  if (e < E) {
    int r   = rows[e];
    int pos = atomicAdd(&fill_cnt[r], 1);
    int at  = row_ptr[r] + pos;
    csr_col[at] = cols[e];
    csr_eid[at] = e;
  }
}

// ---------------------------------------------------------------------------
// Tb = segment_sum(edge_attr) [N][64] bf16; deg from CSR.
// ---------------------------------------------------------------------------
__global__ __launch_bounds__(256) void build_T_deg(
    const float* __restrict__ eattr, const int* __restrict__ row_ptr,
    const int* __restrict__ csr_eid, __hip_bfloat16* __restrict__ Tb,
    float* __restrict__ deg, int N)
{
  int r = blockIdx.x * 4 + (threadIdx.x >> 6);
  if (r >= N) return;
  int lane = threadIdx.x & 63;
  int s = row_ptr[r], len = row_ptr[r + 1] - s;
  float acc = 0.f;
  for (int b = 0; b < len; b += 64) {
    int m  = min(64, len - b);
    int ev = (lane < m) ? csr_eid[s + b + lane] : 0;
    int j  = 0;
    for (; j + 4 <= m; j += 4) {
      int e0 = __shfl(ev, j),     e1 = __shfl(ev, j + 1);
      int e2 = __shfl(ev, j + 2), e3 = __shfl(ev, j + 3);
      float a0 = eattr[(size_t)e0 * 64 + lane];
      float a1 = eattr[(size_t)e1 * 64 + lane];
      float a2 = eattr[(size_t)e2 * 64 + lane];
      float a3 = eattr[(size_t)e3 * 64 + lane];
      acc += (a0 + a1) + (a2 + a3);
    }
    for (; j < m; ++j) {
      int e0 = __shfl(ev, j);
      acc += eattr[(size_t)e0 * 64 + lane];
    }
  }
  Tb[(size_t)r * 64 + lane] = __float2bfloat16(acc);
  if (lane == 0) deg[r] = fmaxf(1.0f, (float)len);
}

// ---------------------------------------------------------------------------
// Per-graph mean pool + hidden relu + output head. One block per graph.
// ---------------------------------------------------------------------------
__global__ __launch_bounds__(128) void pool_head(
    const float* __restrict__ h, const int* __restrict__ batch,
    const float* __restrict__ Wh, const float* __restrict__ bh,
    const float* __restrict__ Wout, const float* __restrict__ bout,
    float* __restrict__ out, int N)
{
  const int g = blockIdx.x;
  const int t = threadIdx.x;
  int lo = 0, hi = N;
  while (lo < hi) { int mid = (lo + hi) >> 1; if (batch[mid] < g) lo = mid + 1; else hi = mid; }
  int start = lo;
  hi = N;
  while (lo < hi) { int mid = (lo + hi) >> 1; if (batch[mid] < g + 1) lo = mid + 1; else hi = mid; }
  int end = lo;

  float s0 = 0.f, s1 = 0.f, s2 = 0.f, s3 = 0.f;
  int i = start;
  for (; i + 4 <= end; i += 4) {
    s0 += h[(size_t)(i + 0) * 128 + t];
    s1 += h[(size_t)(i + 1) * 128 + t];
    s2 += h[(size_t)(i + 2) * 128 + t];
    s3 += h[(size_t)(i + 3) * 128 + t];
  }
  for (; i < end; i++) s0 += h[(size_t)i * 128 + t];
  float sum = (s0 + s1) + (s2 + s3);
  float inv = 1.f / fmaxf(1.f, (float)(end - start));

  __shared__ float gl[128];
  gl[t] = sum * inv;
  __syncthreads();

  float acc = bh[t];
  #pragma unroll 4
  for (int k = 0; k < 128; k++) acc += gl[k] * Wh[k * 128 + t];
  acc = fmaxf(acc, 0.f);

  __shared__ float p[128];
  p[t] = acc * Wout[t];
  __syncthreads();
  if (t < 64) {
    float v = p[t] + p[t + 64];
    #pragma unroll
    for (int o = 32; o > 0; o >>= 1) v += __shfl_down(v, o);
    if (t == 0) out[g] = v + bout[0];
  }
}

// ---------------------------------------------------------------------------
extern "C" void kernel_launch(void* const* d_in, const int* in_sizes, int n_in,
                              void* d_out, int out_size, void* d_ws, size_t ws_size,
                              hipStream_t stream)
{
  const float* x      = (const float*)d_in[0];
  const int*   eidx   = (const int*)d_in[1];
  const float* eattr  = (const float*)d_in[2];
  const int*   batch  = (const int*)d_in[3];
  const float* W_emb  = (const float*)d_in[4];
  const float* b_emb  = (const float*)d_in[5];
  const float* Wc     = (const float*)d_in[6];
  const float* bc     = (const float*)d_in[7];
  const float* gamma  = (const float*)d_in[8];
  const float* beta   = (const float*)d_in[9];
  const float* Wh     = (const float*)d_in[10];
  const float* bh     = (const float*)d_in[11];
  const float* Wout   = (const float*)d_in[12];
  const float* bout   = (const float*)d_in[13];
  float* out = (float*)d_out;

  const int N  = in_sizes[3];
  const int E  = in_sizes[1] / 2;
  const int Fn = in_sizes[0] / N;      // 92
  const int H  = in_sizes[5];          // 128
  const int L  = in_sizes[7] / H;      // 3
  const int Kc = H + in_sizes[2] / E;  // 192
  const int Kp = 96;

  const int* rows = eidx;
  const int* cols = eidx + E;

  char* ws = (char*)d_ws;
  size_t off = 0;
  auto alloc = [&](size_t bytes) { void* p = ws + off; off += (bytes + 255) / 256 * 256; return p; };
  float*           h        = (float*)alloc((size_t)N * 128 * 4);
  __hip_bfloat16*  hbA      = (__hip_bfloat16*)alloc((size_t)N * 128 * 2);
  __hip_bfloat16*  hbB      = (__hip_bfloat16*)alloc((size_t)N * 128 * 2);
  __hip_bfloat16*  Tb       = (__hip_bfloat16*)alloc((size_t)N * 64 * 2);
  __hip_bfloat16*  xb       = (__hip_bfloat16*)alloc((size_t)N * Kp * 2);
  __hip_bfloat16*  Wet      = (__hip_bfloat16*)alloc((size_t)H * Kp * 2);
  __hip_bfloat16*  Wct      = (__hip_bfloat16*)alloc((size_t)L * H * Kc * 2);
  float*           deg      = (float*)alloc((size_t)N * 4);
  int*             row_ptr  = (int*)alloc((size_t)(N + 1) * 4);
  int*             cnt      = (int*)alloc((size_t)N * 4 * 2);
  int*             fill_cnt = cnt + N;
  int*             csr_col  = (int*)alloc((size_t)E * 4);
  int*             csr_eid  = (int*)alloc((size_t)E * 4);
  (void)ws_size; (void)n_in;

  const int prep_total = N * Kp + H * Kp + L * H * Kc;
  prep_all<<<dim3((prep_total + 255) / 256), 256, 0, stream>>>(
      x, xb, W_emb, Wet, Wc, Wct, cnt, N, Fn, Kp, H, L, Kc, prep_total);

  hist_kernel<<<dim3((E + 255) / 256), 256, 0, stream>>>(rows, cnt, E);
  scan_kernel<<<dim3(1), 1024, 0, stream>>>(cnt, row_ptr, N);
  fill_kernel<<<dim3((E + 255) / 256), 256, 0, stream>>>(rows, cols, row_ptr, fill_cnt,
                                                         csr_col, csr_eid, E);
  build_T_deg<<<dim3((N + 3) / 4), 256, 0, stream>>>(eattr, row_ptr, csr_eid, Tb, deg, N);

  gemm_emb_mfma<96><<<dim3((N + 63) / 64), 256, 0, stream>>>(xb, Wet, b_emb, h, hbA, N);

  __hip_bfloat16* hb_in  = hbA;
  __hip_bfloat16* hb_out = hbB;
  for (int l = 0; l < L; l++) {
    conv_fused<<<dim3((N + 63) / 64), 256, 0, stream>>>(
        hb_in, row_ptr, csr_col, Tb, Wct + (size_t)l * H * Kc, deg,
        bc + (size_t)l * H, gamma + (size_t)l * H, beta + (size_t)l * H, h, hb_out, N);
    __hip_bfloat16* tmp = hb_in; hb_in = hb_out; hb_out = tmp;
  }

  pool_head<<<dim3(out_size), 128, 0, stream>>>(h, batch, Wh, bh, Wout, bout, out, N);
}

// Round 6
// 428.743 us; speedup vs baseline: 1.0883x; 1.0883x over previous
//
#include <hip/hip_runtime.h>
#include <hip/hip_bf16.h>
#include <cstdint>
#include <cstddef>

#define BN_EPS 1e-3f

typedef __attribute__((ext_vector_type(8))) short bf16x8;
typedef __attribute__((ext_vector_type(4))) float f32x4;

__device__ __forceinline__ float blo(unsigned u) {
  union { unsigned i; float f; } v; v.i = u << 16; return v.f;
}
__device__ __forceinline__ float bhi(unsigned u) {
  union { unsigned i; float f; } v; v.i = u & 0xffff0000u; return v.f;
}
__device__ __forceinline__ unsigned pk2(float a, float b) {
  __hip_bfloat162 t = __float22bfloat162_rn(make_float2(a, b));
  return *reinterpret_cast<unsigned*>(&t);
}
__device__ __forceinline__ void acc_pk(float* acc, uint4 u) {
  acc[0] += blo(u.x); acc[1] += bhi(u.x);
  acc[2] += blo(u.y); acc[3] += bhi(u.y);
  acc[4] += blo(u.z); acc[5] += bhi(u.z);
  acc[6] += blo(u.w); acc[7] += bhi(u.w);
}

// ---------------------------------------------------------------------------
// Embedding MFMA GEMM reading x fp32 directly (cvt in-register).
// hb = bf16(relu(x @ Wet^T + bias)). 64x128 per block, 4 waves 2x2.
// NOTE: float4 loads rely on Fn*4 and row stride being 16B-aligned (Fn=92 ok).
// ---------------------------------------------------------------------------
template<int KP>
__global__ __launch_bounds__(256) void gemm_emb_mfma(
    const float* __restrict__ x,
    const __hip_bfloat16* __restrict__ Bt,   // [128][KP]
    const float* __restrict__ bias,
    __hip_bfloat16* __restrict__ hb, int N, int Fn)
{
  const int tid  = threadIdx.x;
  const int w    = tid >> 6, lane = tid & 63;
  const int wr   = w >> 1,   wc   = w & 1;
  const int m0   = blockIdx.x * 64;
  const int lr   = lane & 15;
  const int kg   = lane >> 4;

  f32x4 acc[2][4] = {};
  const int rowA0 = m0 + wr * 32 + lr;

  #pragma unroll
  for (int ks = 0; ks < KP / 32; ks++) {
    const int k0 = ks * 32 + kg * 8;
    bf16x8 a[2], b[4];
    #pragma unroll
    for (int m = 0; m < 2; m++) {
      int r = rowA0 + m * 16;
      r = (r < N) ? r : 0;
      const float* px = &x[(size_t)r * Fn + k0];
      float4 v0 = make_float4(0.f, 0.f, 0.f, 0.f);
      float4 v1 = make_float4(0.f, 0.f, 0.f, 0.f);
      if (k0 + 8 <= Fn) {
        v0 = *reinterpret_cast<const float4*>(px);
        v1 = *reinterpret_cast<const float4*>(px + 4);
      } else if (k0 + 4 <= Fn) {
        v0 = *reinterpret_cast<const float4*>(px);
        if (k0 + 5 <= Fn) v1.x = px[4];
        if (k0 + 6 <= Fn) v1.y = px[5];
        if (k0 + 7 <= Fn) v1.z = px[6];
      } else if (k0 < Fn) {
        if (k0 + 1 <= Fn) v0.x = px[0];
        if (k0 + 2 <= Fn) v0.y = px[1];
        if (k0 + 3 <= Fn) v0.z = px[2];
      }
      uint4 pu;
      pu.x = pk2(v0.x, v0.y); pu.y = pk2(v0.z, v0.w);
      pu.z = pk2(v1.x, v1.y); pu.w = pk2(v1.z, v1.w);
      a[m] = *reinterpret_cast<bf16x8*>(&pu);
    }
    #pragma unroll
    for (int n = 0; n < 4; n++) {
      int c = wc * 64 + n * 16 + lr;
      b[n] = *reinterpret_cast<const bf16x8*>(&Bt[(size_t)c * KP + k0]);
    }
    #pragma unroll
    for (int m = 0; m < 2; m++)
      #pragma unroll
      for (int n = 0; n < 4; n++)
        acc[m][n] = __builtin_amdgcn_mfma_f32_16x16x32_bf16(a[m], b[n], acc[m][n], 0, 0, 0);
  }

  #pragma unroll
  for (int n = 0; n < 4; n++) {
    const int c = wc * 64 + n * 16 + lr;
    const float bb = bias[c];
    #pragma unroll
    for (int m = 0; m < 2; m++) {
      #pragma unroll
      for (int j = 0; j < 4; j++) {
        int grow = m0 + wr * 32 + m * 16 + kg * 4 + j;
        if (grow < N) {
          float v = fmaxf(acc[m][n][j] + bb, 0.f);
          hb[(size_t)grow * 128 + c] = __float2bfloat16(v);
        }
      }
    }
  }
}

// ---------------------------------------------------------------------------
// Fused conv layer, bf16 residual chain:
//   hbo = bf16( hbi + relu( (gather(hbi)+T)@Wct / deg * bn_scale + ofs ) )
// Gather phase uses dynamic row assignment (LDS counter) to balance Poisson
// degree skew. hbi/hbo ping-pong (no cross-block race).
// ---------------------------------------------------------------------------
__global__ __launch_bounds__(256) void conv_fused(
    const __hip_bfloat16* __restrict__ hbi,
    const int* __restrict__ row_ptr,
    const int* __restrict__ csr_col,
    const __hip_bfloat16* __restrict__ Tb,    // [N][64]
    const __hip_bfloat16* __restrict__ Wct,   // [128][192]
    const float* __restrict__ deg,
    const float* __restrict__ bc,
    const float* __restrict__ gamma,
    const float* __restrict__ beta,
    __hip_bfloat16* __restrict__ hbo, int N)
{
  constexpr int K   = 192;
  constexpr int LDK = 200;
  __shared__ __hip_bfloat16 As[64 * LDK];   // 25.6 KB
  __shared__ int next_row;

  const int tid = threadIdx.x;
  const int m0  = blockIdx.x * 64;
  if (tid == 0) next_row = 16;
  __syncthreads();

  // ---- gather phase: 16 groups x 16 lanes, dynamic row pop
  {
    const int g   = tid >> 4;
    const int gl  = tid & 15;
    const int wl  = tid & 63;
    const int gb  = wl & ~15;       // group base lane within wave (for shfl)
    int r = g;
    while (r < 64) {
      const int gr = m0 + r;
      float acc[8] = {};
      if (gr < N) {
        const int s   = row_ptr[gr];
        const int len = row_ptr[gr + 1] - s;
        for (int b = 0; b < len; b += 16) {
          const int m  = min(16, len - b);
          const int cv = (gl < m) ? csr_col[s + b + gl] : 0;
          int j = 0;
          for (; j + 8 <= m; j += 8) {
            uint4 u[8];
            #pragma unroll
            for (int t = 0; t < 8; t++) {
              int c = __shfl(cv, gb + j + t);
              u[t] = *reinterpret_cast<const uint4*>(&hbi[(size_t)c * 128 + gl * 8]);
            }
            #pragma unroll
            for (int t = 0; t < 8; t++) acc_pk(acc, u[t]);
          }
          for (; j + 4 <= m; j += 4) {
            uint4 u[4];
            #pragma unroll
            for (int t = 0; t < 4; t++) {
              int c = __shfl(cv, gb + j + t);
              u[t] = *reinterpret_cast<const uint4*>(&hbi[(size_t)c * 128 + gl * 8]);
            }
            #pragma unroll
            for (int t = 0; t < 4; t++) acc_pk(acc, u[t]);
          }
          for (; j < m; ++j) {
            int c = __shfl(cv, gb + j);
            uint4 u = *reinterpret_cast<const uint4*>(&hbi[(size_t)c * 128 + gl * 8]);
            acc_pk(acc, u);
          }
        }
      }
      uint4 o;
      o.x = pk2(acc[0], acc[1]); o.y = pk2(acc[2], acc[3]);
      o.z = pk2(acc[4], acc[5]); o.w = pk2(acc[6], acc[7]);
      *reinterpret_cast<uint4*>(&As[r * LDK + gl * 8]) = o;
      if (gl == 0) r = atomicAdd(&next_row, 1);
      r = __shfl(r, gb);
    }
  }
  // ---- T-tile copy: 64 rows x 64 cols bf16
  #pragma unroll
  for (int it = 0; it < 2; it++) {
    int idx = tid + it * 256;
    int r   = idx >> 3;
    int ko  = (idx & 7) * 8;
    int gr  = m0 + r;
    uint4 v = make_uint4(0, 0, 0, 0);
    if (gr < N) v = *reinterpret_cast<const uint4*>(&Tb[(size_t)gr * 64 + ko]);
    *reinterpret_cast<uint4*>(&As[r * LDK + 128 + ko]) = v;
  }
  __syncthreads();

  // ---- MFMA phase
  const int w    = tid >> 6, lane = tid & 63;
  const int wr   = w >> 1,   wc   = w & 1;
  const int lr   = lane & 15;
  const int kg   = lane >> 4;

  f32x4 acc[2][4] = {};
  #pragma unroll
  for (int ks = 0; ks < K / 32; ks++) {
    const int k0 = ks * 32 + kg * 8;
    bf16x8 a[2], b[4];
    #pragma unroll
    for (int m = 0; m < 2; m++) {
      int r = wr * 32 + lr + m * 16;
      a[m] = *reinterpret_cast<const bf16x8*>(&As[r * LDK + k0]);
    }
    #pragma unroll
    for (int n = 0; n < 4; n++) {
      int c = wc * 64 + n * 16 + lr;
      b[n] = *reinterpret_cast<const bf16x8*>(&Wct[(size_t)c * K + k0]);
    }
    #pragma unroll
    for (int m = 0; m < 2; m++)
      #pragma unroll
      for (int n = 0; n < 4; n++)
        acc[m][n] = __builtin_amdgcn_mfma_f32_16x16x32_bf16(a[m], b[n], acc[m][n], 0, 0, 0);
  }

  const float rs = rsqrtf(1.f + BN_EPS);
  #pragma unroll
  for (int n = 0; n < 4; n++) {
    const int c   = wc * 64 + n * 16 + lr;
    const float sc  = gamma[c] * rs;
    const float ofs = bc[c] * sc + beta[c];
    #pragma unroll
    for (int m = 0; m < 2; m++) {
      #pragma unroll
      for (int j = 0; j < 4; j++) {
        int grow = m0 + wr * 32 + m * 16 + kg * 4 + j;
        if (grow < N) {
          float id   = 1.f / deg[grow];
          float v    = acc[m][n][j] * sc * id + ofs;
          float hold = __bfloat162float(hbi[(size_t)grow * 128 + c]);
          float hn   = hold + fmaxf(v, 0.f);
          hbo[(size_t)grow * 128 + c] = __float2bfloat16(hn);
        }
      }
    }
  }
}

// ---------------------------------------------------------------------------
// One-shot prep: Wet [128][96] bf16 (transposed, padded), Wct [L][128][192]
// bf16 (transposed), zero cnt/fill_cnt.
// ---------------------------------------------------------------------------
__global__ void prep_all(const float* __restrict__ W_emb, __hip_bfloat16* __restrict__ Wet,
                         const float* __restrict__ Wc, __hip_bfloat16* __restrict__ Wct,
                         int* __restrict__ cnt,
                         int N, int Fn, int Kp, int H, int L, int Kc)
{
  int i = blockIdx.x * 256 + threadIdx.x;
  if (i < H * Kp) {
    int c = i / Kp, k = i - c * Kp;
    Wet[i] = __float2bfloat16(k < Fn ? W_emb[(size_t)k * H + c] : 0.f);
  } else if (i < H * Kp + L * H * Kc) {
    int j = i - H * Kp;
    int l   = j / (H * Kc);
    int rem = j - l * (H * Kc);
    int c   = rem / Kc;
    int k   = rem - c * Kc;
    Wct[j] = __float2bfloat16(Wc[(size_t)l * Kc * H + (size_t)k * H + c]);
  }
  if (i < 2 * N) cnt[i] = 0;
}

// ---------------------------------------------------------------------------
// CSR build
// ---------------------------------------------------------------------------
__global__ void hist_kernel(const int* __restrict__ rows, int* __restrict__ cnt, int E) {
  int e = blockIdx.x * 256 + threadIdx.x;
  if (e < E) atomicAdd(&cnt[rows[e]], 1);
}

__global__ __launch_bounds__(1024) void scan_kernel(const int* __restrict__ cnt,
                                                    int* __restrict__ row_ptr, int N) {
  __shared__ int wsum[16];
  __shared__ int woff[16];
  __shared__ int carry;
  const int tid  = threadIdx.x;
  const int lane = tid & 63, wid = tid >> 6;
  if (tid == 0) { carry = 0; row_ptr[0] = 0; }
  __syncthreads();
  for (int base = 0; base < N; base += 8192) {
    int c = carry;
    int v[8]; int s = 0;
    #pragma unroll
    for (int i = 0; i < 8; i++) {
      int idx = base + tid * 8 + i;
      v[i] = (idx < N) ? cnt[idx] : 0;
      s += v[i];
    }
    int sc = s;
    #pragma unroll
    for (int o = 1; o < 64; o <<= 1) {
      int u = __shfl_up(sc, o);
      if (lane >= o) sc += u;
    }
    if (lane == 63) wsum[wid] = sc;
    __syncthreads();
    if (tid == 0) {
      int run = 0;
      for (int i = 0; i < 16; i++) { int t = wsum[i]; woff[i] = run; run += t; }
      carry = c + run;
    }
    __syncthreads();
    int run = c + woff[wid] + (sc - s);
    #pragma unroll
    for (int i = 0; i < 8; i++) {
      int idx = base + tid * 8 + i;
      run += v[i];
      if (idx < N) row_ptr[idx + 1] = run;
    }
  }
}

__global__ void fill_kernel(const int* __restrict__ rows, const int* __restrict__ cols,
                            const int* __restrict__ row_ptr, int* __restrict__ fill_cnt,
                            int* __restrict__ csr_col, int* __restrict__ csr_eid, int E) {
  int e = blockIdx.x * 256 + threadIdx.x;
  if (e < E) {
    int r   = rows[e];
    int pos = atomicAdd(&fill_cnt[r], 1);
    int at  = row_ptr[r] + pos;
    csr_col[at] = cols[e];
    csr_eid[at] = e;
  }
}

// ---------------------------------------------------------------------------
// Tb = segment_sum(edge_attr) [N][64] bf16; deg from CSR.
// ---------------------------------------------------------------------------
__global__ __launch_bounds__(256) void build_T_deg(
    const float* __restrict__ eattr, const int* __restrict__ row_ptr,
    const int* __restrict__ csr_eid, __hip_bfloat16* __restrict__ Tb,
    float* __restrict__ deg, int N)
{
  int r = blockIdx.x * 4 + (threadIdx.x >> 6);
  if (r >= N) return;
  int lane = threadIdx.x & 63;
  int s = row_ptr[r], len = row_ptr[r + 1] - s;
  float acc = 0.f;
  for (int b = 0; b < len; b += 64) {
    int m  = min(64, len - b);
    int ev = (lane < m) ? csr_eid[s + b + lane] : 0;
    int j  = 0;
    for (; j + 4 <= m; j += 4) {
      int e0 = __shfl(ev, j),     e1 = __shfl(ev, j + 1);
      int e2 = __shfl(ev, j + 2), e3 = __shfl(ev, j + 3);
      float a0 = eattr[(size_t)e0 * 64 + lane];
      float a1 = eattr[(size_t)e1 * 64 + lane];
      float a2 = eattr[(size_t)e2 * 64 + lane];
      float a3 = eattr[(size_t)e3 * 64 + lane];
      acc += (a0 + a1) + (a2 + a3);
    }
    for (; j < m; ++j) {
      int e0 = __shfl(ev, j);
      acc += eattr[(size_t)e0 * 64 + lane];
    }
  }
  Tb[(size_t)r * 64 + lane] = __float2bfloat16(acc);
  if (lane == 0) deg[r] = fmaxf(1.0f, (float)len);
}

// ---------------------------------------------------------------------------
// Per-graph mean pool (bf16 h) + hidden relu + output head. One block/graph.
// ---------------------------------------------------------------------------
__global__ __launch_bounds__(128) void pool_head(
    const __hip_bfloat16* __restrict__ hb, const int* __restrict__ batch,
    const float* __restrict__ Wh, const float* __restrict__ bh,
    const float* __restrict__ Wout, const float* __restrict__ bout,
    float* __restrict__ out, int N)
{
  const int g = blockIdx.x;
  const int t = threadIdx.x;
  int lo = 0, hi = N;
  while (lo < hi) { int mid = (lo + hi) >> 1; if (batch[mid] < g) lo = mid + 1; else hi = mid; }
  int start = lo;
  hi = N;
  while (lo < hi) { int mid = (lo + hi) >> 1; if (batch[mid] < g + 1) lo = mid + 1; else hi = mid; }
  int end = lo;

  const int lane = t & 63, half = t >> 6;
  float2 a0 = {0.f, 0.f}, a1 = {0.f, 0.f}, a2 = {0.f, 0.f}, a3 = {0.f, 0.f};
  int i = start + half;
  for (; i + 6 < end; i += 8) {
    unsigned u0 = *reinterpret_cast<const unsigned*>(&hb[(size_t)(i + 0) * 128 + lane * 2]);
    unsigned u1 = *reinterpret_cast<const unsigned*>(&hb[(size_t)(i + 2) * 128 + lane * 2]);
    unsigned u2 = *reinterpret_cast<const unsigned*>(&hb[(size_t)(i + 4) * 128 + lane * 2]);
    unsigned u3 = *reinterpret_cast<const unsigned*>(&hb[(size_t)(i + 6) * 128 + lane * 2]);
    a0.x += blo(u0); a0.y += bhi(u0);
    a1.x += blo(u1); a1.y += bhi(u1);
    a2.x += blo(u2); a2.y += bhi(u2);
    a3.x += blo(u3); a3.y += bhi(u3);
  }
  for (; i < end; i += 2) {
    unsigned u = *reinterpret_cast<const unsigned*>(&hb[(size_t)i * 128 + lane * 2]);
    a0.x += blo(u); a0.y += bhi(u);
  }
  float2 sum;
  sum.x = (a0.x + a1.x) + (a2.x + a3.x);
  sum.y = (a0.y + a1.y) + (a2.y + a3.y);

  __shared__ float2 part[2][64];
  __shared__ float  gl[128];
  part[half][lane] = sum;
  __syncthreads();
  if (t < 64) {
    float inv = 1.f / fmaxf(1.f, (float)(end - start));
    float2 tot;
    tot.x = part[0][t].x + part[1][t].x;
    tot.y = part[0][t].y + part[1][t].y;
    gl[2 * t]     = tot.x * inv;
    gl[2 * t + 1] = tot.y * inv;
  }
  __syncthreads();

  float acc = bh[t];
  #pragma unroll 4
  for (int k = 0; k < 128; k++) acc += gl[k] * Wh[k * 128 + t];
  acc = fmaxf(acc, 0.f);

  __shared__ float p[128];
  p[t] = acc * Wout[t];
  __syncthreads();
  if (t < 64) {
    float v = p[t] + p[t + 64];
    #pragma unroll
    for (int o = 32; o > 0; o >>= 1) v += __shfl_down(v, o);
    if (t == 0) out[g] = v + bout[0];
  }
}

// ---------------------------------------------------------------------------
extern "C" void kernel_launch(void* const* d_in, const int* in_sizes, int n_in,
                              void* d_out, int out_size, void* d_ws, size_t ws_size,
                              hipStream_t stream)
{
  const float* x      = (const float*)d_in[0];
  const int*   eidx   = (const int*)d_in[1];
  const float* eattr  = (const float*)d_in[2];
  const int*   batch  = (const int*)d_in[3];
  const float* W_emb  = (const float*)d_in[4];
  const float* b_emb  = (const float*)d_in[5];
  const float* Wc     = (const float*)d_in[6];
  const float* bc     = (const float*)d_in[7];
  const float* gamma  = (const float*)d_in[8];
  const float* beta   = (const float*)d_in[9];
  const float* Wh     = (const float*)d_in[10];
  const float* bh     = (const float*)d_in[11];
  const float* Wout   = (const float*)d_in[12];
  const float* bout   = (const float*)d_in[13];
  float* out = (float*)d_out;

  const int N  = in_sizes[3];
  const int E  = in_sizes[1] / 2;
  const int Fn = in_sizes[0] / N;      // 92
  const int H  = in_sizes[5];          // 128
  const int L  = in_sizes[7] / H;      // 3
  const int Kc = H + in_sizes[2] / E;  // 192
  const int Kp = 96;

  const int* rows = eidx;
  const int* cols = eidx + E;

  char* ws = (char*)d_ws;
  size_t off = 0;
  auto alloc = [&](size_t bytes) { void* p = ws + off; off += (bytes + 255) / 256 * 256; return p; };
  __hip_bfloat16*  hbA      = (__hip_bfloat16*)alloc((size_t)N * 128 * 2);
  __hip_bfloat16*  hbB      = (__hip_bfloat16*)alloc((size_t)N * 128 * 2);
  __hip_bfloat16*  Tb       = (__hip_bfloat16*)alloc((size_t)N * 64 * 2);
  __hip_bfloat16*  Wet      = (__hip_bfloat16*)alloc((size_t)H * Kp * 2);
  __hip_bfloat16*  Wct      = (__hip_bfloat16*)alloc((size_t)L * H * Kc * 2);
  float*           deg      = (float*)alloc((size_t)N * 4);
  int*             row_ptr  = (int*)alloc((size_t)(N + 1) * 4);
  int*             cnt      = (int*)alloc((size_t)N * 4 * 2);
  int*             fill_cnt = cnt + N;
  int*             csr_col  = (int*)alloc((size_t)E * 4);
  int*             csr_eid  = (int*)alloc((size_t)E * 4);
  (void)ws_size; (void)n_in;

  int prep_total = H * Kp + L * H * Kc;
  if (prep_total < 2 * N) prep_total = 2 * N;
  prep_all<<<dim3((prep_total + 255) / 256), 256, 0, stream>>>(
      W_emb, Wet, Wc, Wct, cnt, N, Fn, Kp, H, L, Kc);

  hist_kernel<<<dim3((E + 255) / 256), 256, 0, stream>>>(rows, cnt, E);
  scan_kernel<<<dim3(1), 1024, 0, stream>>>(cnt, row_ptr, N);
  fill_kernel<<<dim3((E + 255) / 256), 256, 0, stream>>>(rows, cols, row_ptr, fill_cnt,
                                                         csr_col, csr_eid, E);
  build_T_deg<<<dim3((N + 3) / 4), 256, 0, stream>>>(eattr, row_ptr, csr_eid, Tb, deg, N);

  gemm_emb_mfma<96><<<dim3((N + 63) / 64), 256, 0, stream>>>(x, Wet, b_emb, hbA, N, Fn);

  __hip_bfloat16* hb_in  = hbA;
  __hip_bfloat16* hb_out = hbB;
  for (int l = 0; l < L; l++) {
    conv_fused<<<dim3((N + 63) / 64), 256, 0, stream>>>(
        hb_in, row_ptr, csr_col, Tb, Wct + (size_t)l * H * Kc, deg,
        bc + (size_t)l * H, gamma + (size_t)l * H, beta + (size_t)l * H, hb_out, N);
    __hip_bfloat16* tmp = hb_in; hb_in = hb_out; hb_out = tmp;
  }

  pool_head<<<dim3(out_size), 128, 0, stream>>>(hb_in, batch, Wh, bh, Wout, bout, out, N);
}